// Round 1
// baseline (6576.742 us; speedup 1.0000x reference)
//
#include <hip/hip_runtime.h>

// C = tril(tril(A) @ tril(B)), N=4096, fp32.
// Baseline: tile-skipping fp32 vector SGEMM.
//   - 128x128 block tile, BK=16, 256 threads, 8x8 micro-tile/thread
//   - k-tiles restricted to [bj*128, (bi+1)*128)
//   - A masked (k<=i) and B masked (j<=k) at LDS-fill; diagonal tile output masked
//   - strictly-upper tiles write zeros (d_out is poisoned before every launch)
// Next step (round 2): bf16x3 split-fp32 MFMA path.

constexpr int N_DIM = 4096;
constexpr int BM = 128, BN = 128, BK = 16;
constexpr int PAD = 132;   // LDS row pitch (floats); breaks scatter-write bank conflicts
constexpr int NT = N_DIM / BM;  // 32 tiles per dim

__global__ __launch_bounds__(256, 4)
void trimm_fp32(const float* __restrict__ A,
                const float* __restrict__ B,
                float* __restrict__ C) {
    const int bj = blockIdx.x;   // col tile
    const int bi = blockIdx.y;   // row tile
    const int r0 = bi * BM;
    const int c0 = bj * BN;
    const int tid = threadIdx.x;
    const int tx = tid & 15;
    const int ty = tid >> 4;

    if (bj > bi) {
        // strictly above the diagonal: output is exactly zero — write it
        const float4 z = make_float4(0.f, 0.f, 0.f, 0.f);
        #pragma unroll
        for (int hi = 0; hi < 2; ++hi)
        #pragma unroll
        for (int ii = 0; ii < 4; ++ii) {
            const int i = r0 + hi * 64 + ty * 4 + ii;
            #pragma unroll
            for (int hj = 0; hj < 2; ++hj) {
                const int j = c0 + hj * 64 + tx * 4;
                *reinterpret_cast<float4*>(&C[(size_t)i * N_DIM + j]) = z;
            }
        }
        return;
    }

    __shared__ float As[BK][PAD];   // As[k][row]  (A tile stored K-major)
    __shared__ float Bs[BK][PAD];   // Bs[k][col]

    float acc[8][8];
    #pragma unroll
    for (int i = 0; i < 8; ++i)
        #pragma unroll
        for (int j = 0; j < 8; ++j) acc[i][j] = 0.f;

    const int kt_begin = bj * (BN / BK);        // first k-tile: k >= c0
    const int kt_end   = (bi + 1) * (BM / BK);  // last k-tile:  k <= r0+BM-1

    for (int kt = kt_begin; kt < kt_end; ++kt) {
        const int k0 = kt * BK;
        __syncthreads();   // previous compute done before overwriting LDS

        // ---- A tile: As[k][row] = (k <= r0+row) ? A[r0+row][k] : 0
        #pragma unroll
        for (int g = 0; g < 2; ++g) {
            const int idx = tid + g * 256;      // 0..511
            const int row = idx >> 2;           // 0..127
            const int kq  = (idx & 3) * 4;      // 0,4,8,12
            const float4 v = *reinterpret_cast<const float4*>(
                &A[(size_t)(r0 + row) * N_DIM + k0 + kq]);
            const float vv[4] = {v.x, v.y, v.z, v.w};
            #pragma unroll
            for (int e = 0; e < 4; ++e) {
                const int k = k0 + kq + e;
                As[kq + e][row] = (k <= r0 + row) ? vv[e] : 0.f;
            }
        }
        // ---- B tile: Bs[k][col] = (col <= k) ? B[k][col] : 0
        #pragma unroll
        for (int g = 0; g < 2; ++g) {
            const int idx = tid + g * 256;      // 0..511
            const int kk  = idx >> 5;           // 0..15
            const int cq  = (idx & 31) * 4;     // 0..124
            float4 v = *reinterpret_cast<const float4*>(
                &B[(size_t)(k0 + kk) * N_DIM + c0 + cq]);
            const int k = k0 + kk;
            v.x = (c0 + cq + 0 <= k) ? v.x : 0.f;
            v.y = (c0 + cq + 1 <= k) ? v.y : 0.f;
            v.z = (c0 + cq + 2 <= k) ? v.z : 0.f;
            v.w = (c0 + cq + 3 <= k) ? v.w : 0.f;
            *reinterpret_cast<float4*>(&Bs[kk][cq]) = v;
        }
        __syncthreads();

        // ---- 8x8 outer-product FMA
        #pragma unroll
        for (int kk = 0; kk < BK; ++kk) {
            float a[8], b[8];
            *reinterpret_cast<float4*>(&a[0]) =
                *reinterpret_cast<const float4*>(&As[kk][ty * 4]);
            *reinterpret_cast<float4*>(&a[4]) =
                *reinterpret_cast<const float4*>(&As[kk][64 + ty * 4]);
            *reinterpret_cast<float4*>(&b[0]) =
                *reinterpret_cast<const float4*>(&Bs[kk][tx * 4]);
            *reinterpret_cast<float4*>(&b[4]) =
                *reinterpret_cast<const float4*>(&Bs[kk][64 + tx * 4]);
            #pragma unroll
            for (int i = 0; i < 8; ++i)
                #pragma unroll
                for (int j = 0; j < 8; ++j)
                    acc[i][j] = fmaf(a[i], b[j], acc[i][j]);
        }
    }

    // ---- epilogue: store, masking the diagonal tile to lower-triangular
    const bool diag = (bi == bj);
    #pragma unroll
    for (int hi = 0; hi < 2; ++hi)
    #pragma unroll
    for (int ii = 0; ii < 4; ++ii) {
        const int i = r0 + hi * 64 + ty * 4 + ii;
        #pragma unroll
        for (int hj = 0; hj < 2; ++hj) {
            const int j = c0 + hj * 64 + tx * 4;
            float4 v;
            v.x = acc[hi * 4 + ii][hj * 4 + 0];
            v.y = acc[hi * 4 + ii][hj * 4 + 1];
            v.z = acc[hi * 4 + ii][hj * 4 + 2];
            v.w = acc[hi * 4 + ii][hj * 4 + 3];
            if (diag) {
                if (j + 0 > i) v.x = 0.f;
                if (j + 1 > i) v.y = 0.f;
                if (j + 2 > i) v.z = 0.f;
                if (j + 3 > i) v.w = 0.f;
            }
            *reinterpret_cast<float4*>(&C[(size_t)i * N_DIM + j]) = v;
        }
    }
}

extern "C" void kernel_launch(void* const* d_in, const int* in_sizes, int n_in,
                              void* d_out, int out_size, void* d_ws, size_t ws_size,
                              hipStream_t stream) {
    const float* A = (const float*)d_in[0];
    const float* B = (const float*)d_in[1];
    float* C = (float*)d_out;
    dim3 grid(NT, NT);
    dim3 block(256);
    hipLaunchKernelGGL(trimm_fp32, grid, block, 0, stream, A, B, C);
}

// Round 3
// 327.614 us; speedup vs baseline: 20.0746x; 20.0746x over previous
//
#include <hip/hip_runtime.h>

// C = tril(tril(A) @ tril(B)), N=4096, fp32 in/out.
// Round 3: bf16x3 split MFMA, NO unverified HW semantics (tr_read removed).
//   - 128x128 tile, BK=32, 256 threads (2x2 waves, 4x4 16x16 frags/wave)
//   - fp32 -> (hi,lo) bf16 split in-register at staging; C += Ah*Bh + Ah*Bl + Al*Bh
//   - A in LDS row-major [128][40]; B stored TRANSPOSED [col][k] pitch 40
//     -> both fragments are contiguous short8 reads (m92-verified pattern)
//   - masks hoisted: A-mask only on last 4 k-tiles, B-mask only on first 4
//   - heavy-first 1D remap of lower tiles; strictly-upper tiles zero-fill

typedef __attribute__((ext_vector_type(8))) short short8;   // 8 bf16 (4 VGPR)
typedef __attribute__((ext_vector_type(4))) float f32x4;    // MFMA C/D frag
typedef __attribute__((ext_vector_type(2))) unsigned int u32x2;

constexpr int N_DIM = 4096;
constexpr int BM = 128, BN = 128, BK = 32;
constexpr int NT = N_DIM / BM;             // 32
constexpr int N_LOWER = NT * (NT + 1) / 2; // 528
constexpr int LP = 40;                     // LDS pitch (shorts): 80 B, 16B-divisible

__device__ __forceinline__ void split2(float x, unsigned& h, unsigned& l) {
    const unsigned u = __float_as_uint(x);
    h = (u + 0x7FFFu + ((u >> 16) & 1u)) >> 16;     // RNE hi
    const float r = x - __uint_as_float(h << 16);   // exact residual
    l = __float_as_uint(r) >> 16;                   // truncated lo (error 2^-15 rel)
}

__global__ __launch_bounds__(256)
void trimm_bf16x3(const float* __restrict__ A, const float* __restrict__ B,
                  float* __restrict__ C) {
    const int tid = threadIdx.x;
    const int id = blockIdx.x;

    if (id >= N_LOWER) {
        // strictly-upper tile: exact zeros (output re-poisoned each launch)
        int u = id - N_LOWER, bi = 0;
        while (u >= NT - 1 - bi) { u -= NT - 1 - bi; ++bi; }
        const int bj = bi + 1 + u;
        const int r0 = bi * BM, c0 = bj * BN;
        const float4 z = make_float4(0.f, 0.f, 0.f, 0.f);
        #pragma unroll
        for (int r = 0; r < 16; ++r) {
            const int f = r * 256 + tid;
            *reinterpret_cast<float4*>(
                &C[(size_t)(r0 + (f >> 5)) * N_DIM + c0 + (f & 31) * 4]) = z;
        }
        return;
    }

    // heavy-first: dr=0 -> farthest-from-diagonal (most k-tiles) first
    int dr = (int)((sqrtf(8.f * (float)id + 1.f) - 1.f) * 0.5f);
    dr = dr < 0 ? 0 : (dr > NT - 1 ? NT - 1 : dr);
    while (dr * (dr + 1) / 2 > id) --dr;
    while ((dr + 1) * (dr + 2) / 2 <= id) ++dr;
    const int bj = id - dr * (dr + 1) / 2;
    const int bi = bj + (NT - 1 - dr);
    const int r0 = bi * BM, c0 = bj * BN;

    __shared__ __align__(16) unsigned short AsH[BM][LP];   // [row][k]
    __shared__ __align__(16) unsigned short AsL[BM][LP];
    __shared__ __align__(16) unsigned short BsH[BN][LP];   // [col][k]  (B^T)
    __shared__ __align__(16) unsigned short BsL[BN][LP];

    const int lane = tid & 63, w = tid >> 6;
    const int wm = w >> 1, wn = w & 1;          // wave -> 64x64 quadrant
    const int l15 = lane & 15, l4 = lane >> 4;

    f32x4 acc[4][4];
    #pragma unroll
    for (int m = 0; m < 4; ++m)
        #pragma unroll
        for (int n = 0; n < 4; ++n) acc[m][n] = (f32x4){0.f, 0.f, 0.f, 0.f};

    const int kt0 = bj * (BN / BK);          // k >= c0
    const int kt1 = (bi + 1) * (BM / BK);    // k <= r0+127
    const int ktA = bi * (BM / BK);          // kt >= ktA -> A-mask (k<=i) can bite
    const int ktB = (bj + 1) * (BN / BK);    // kt <  ktB -> B-mask (j<=k) can bite

    for (int kt = kt0; kt < kt1; ++kt) {
        const int k0 = kt * BK;
        __syncthreads();   // prev iteration's fragment reads done

        // ---- global loads first (all in-bounds, unmasked)
        float4 ga[4];
        float gb[4][4];
        #pragma unroll
        for (int r = 0; r < 4; ++r) {
            const int f = r * 256 + tid;                 // A: row=f>>3, pos=f&7
            ga[r] = *reinterpret_cast<const float4*>(
                &A[(size_t)(r0 + (f >> 3)) * N_DIM + k0 + (f & 7) * 4]);
        }
        #pragma unroll
        for (int r = 0; r < 4; ++r) {
            const int f = r * 256 + tid;                 // B: col=f&127, kq=(f>>7)*4
            const int col = f & 127, kq = (f >> 7) * 4;
            const float* bp = &B[(size_t)(k0 + kq) * N_DIM + c0 + col];
            #pragma unroll
            for (int e = 0; e < 4; ++e) gb[r][e] = bp[(size_t)e * N_DIM];
        }

        const bool mA = (kt >= ktA);   // block-uniform
        const bool mB = (kt < ktB);

        // ---- A: (mask) split, store row-major
        #pragma unroll
        for (int r = 0; r < 4; ++r) {
            const int f = r * 256 + tid;
            const int row = f >> 3, pos = f & 7;
            float v[4] = {ga[r].x, ga[r].y, ga[r].z, ga[r].w};
            if (mA) {
                const int ig = r0 + row, kg = k0 + pos * 4;
                #pragma unroll
                for (int e = 0; e < 4; ++e) v[e] = (kg + e <= ig) ? v[e] : 0.f;
            }
            unsigned h[4], l[4];
            #pragma unroll
            for (int e = 0; e < 4; ++e) split2(v[e], h[e], l[e]);
            *reinterpret_cast<u32x2*>(&AsH[row][pos * 4]) =
                (u32x2){h[0] | (h[1] << 16), h[2] | (h[3] << 16)};
            *reinterpret_cast<u32x2*>(&AsL[row][pos * 4]) =
                (u32x2){l[0] | (l[1] << 16), l[2] | (l[3] << 16)};
        }
        // ---- B: (mask) split, store transposed [col][k]
        #pragma unroll
        for (int r = 0; r < 4; ++r) {
            const int f = r * 256 + tid;
            const int col = f & 127, kq = (f >> 7) * 4;
            float v[4] = {gb[r][0], gb[r][1], gb[r][2], gb[r][3]};
            if (mB) {
                const int jg = c0 + col, kg = k0 + kq;
                #pragma unroll
                for (int e = 0; e < 4; ++e) v[e] = (jg <= kg + e) ? v[e] : 0.f;
            }
            unsigned h[4], l[4];
            #pragma unroll
            for (int e = 0; e < 4; ++e) split2(v[e], h[e], l[e]);
            *reinterpret_cast<u32x2*>(&BsH[col][kq]) =
                (u32x2){h[0] | (h[1] << 16), h[2] | (h[3] << 16)};
            *reinterpret_cast<u32x2*>(&BsL[col][kq]) =
                (u32x2){l[0] | (l[1] << 16), l[2] | (l[3] << 16)};
        }
        __syncthreads();

        // ---- fragments: contiguous short8 for BOTH operands
        short8 aH[4], aL[4], bH[4], bL[4];
        #pragma unroll
        for (int m = 0; m < 4; ++m) {
            const int row = wm * 64 + m * 16 + l15;
            aH[m] = *reinterpret_cast<const short8*>(&AsH[row][l4 * 8]);
            aL[m] = *reinterpret_cast<const short8*>(&AsL[row][l4 * 8]);
        }
        #pragma unroll
        for (int n = 0; n < 4; ++n) {
            const int col = wn * 64 + n * 16 + l15;
            bH[n] = *reinterpret_cast<const short8*>(&BsH[col][l4 * 8]);
            bL[n] = *reinterpret_cast<const short8*>(&BsL[col][l4 * 8]);
        }

        // ---- bf16x3: acc += Ah*Bh + Ah*Bl + Al*Bh
        #pragma unroll
        for (int m = 0; m < 4; ++m)
            #pragma unroll
            for (int n = 0; n < 4; ++n) {
                acc[m][n] = __builtin_amdgcn_mfma_f32_16x16x32_bf16(aH[m], bH[n], acc[m][n], 0, 0, 0);
                acc[m][n] = __builtin_amdgcn_mfma_f32_16x16x32_bf16(aH[m], bL[n], acc[m][n], 0, 0, 0);
                acc[m][n] = __builtin_amdgcn_mfma_f32_16x16x32_bf16(aL[m], bH[n], acc[m][n], 0, 0, 0);
            }
    }

    // ---- epilogue: C/D layout col=l&15, row=(l>>4)*4+reg (m89-verified)
    const bool diag = (bi == bj);
    #pragma unroll
    for (int m = 0; m < 4; ++m) {
        const int i0 = r0 + wm * 64 + m * 16 + l4 * 4;
        #pragma unroll
        for (int n = 0; n < 4; ++n) {
            const int j = c0 + wn * 64 + n * 16 + l15;
            #pragma unroll
            for (int r = 0; r < 4; ++r) {
                float val = acc[m][n][r];
                if (diag && (j > i0 + r)) val = 0.f;
                C[(size_t)(i0 + r) * N_DIM + j] = val;
            }
        }
    }
}

extern "C" void kernel_launch(void* const* d_in, const int* in_sizes, int n_in,
                              void* d_out, int out_size, void* d_ws, size_t ws_size,
                              hipStream_t stream) {
    const float* A = (const float*)d_in[0];
    const float* B = (const float*)d_in[1];
    float* C = (float*)d_out;
    dim3 grid(NT * NT);
    dim3 block(256);
    hipLaunchKernelGGL(trimm_bf16x3, grid, block, 0, stream, A, B, C);
}

// Round 4
// 325.934 us; speedup vs baseline: 20.1781x; 1.0052x over previous
//
#include <hip/hip_runtime.h>

// C = tril(tril(A) @ tril(B)), N=4096, fp32 in/out.
// Round 4: pre-split bf16 planes in d_ws + pure-bf16 MFMA GEMM.
//   Pass S1: Ah/Al = split(tril(A)), bf16 row-major (only tiles tk<=ti).
//   Pass S2: BtH/BtL = split(tril(B))^T as [col][k] (only tiles tk64>=(tj64&~1)).
//   Pass G : m97-class 128x128/BK=32 GEMM, global_load_lds width=16,
//            both-sides XOR swizzle (rule #21): srcslot = slot ^ ((row>>1)&3),
//            same XOR on ds_read -> conflict-free b128 fragment reads.
//   Fallback (ws too small): round-3 in-loop-split kernel (verified pass).

typedef __attribute__((ext_vector_type(8))) short short8;   // 8 bf16 (4 VGPR)
typedef __attribute__((ext_vector_type(4))) float f32x4;
typedef __attribute__((ext_vector_type(2))) unsigned int u32x2;
typedef __attribute__((ext_vector_type(4))) unsigned int u32x4;

constexpr int N_DIM = 4096;
constexpr int BM = 128, BN = 128, BK = 32;
constexpr int NT = N_DIM / BM;             // 32
constexpr int N_LOWER = NT * (NT + 1) / 2; // 528

__device__ __forceinline__ void split2(float x, unsigned& h, unsigned& l) {
    const unsigned u = __float_as_uint(x);
    h = (u + 0x7FFFu + ((u >> 16) & 1u)) >> 16;     // RNE hi
    const float r = x - __uint_as_float(h << 16);   // exact residual
    l = __float_as_uint(r) >> 16;                   // truncated lo
}

__device__ __forceinline__ void gload_lds16(const void* g, void* l) {
    __builtin_amdgcn_global_load_lds(
        (const __attribute__((address_space(1))) void*)g,
        (__attribute__((address_space(3))) void*)l, 16, 0, 0);
}

// ---------------- S1: A -> Ah/Al (masked, row-major), lower tiles only ----------
__global__ __launch_bounds__(256)
void split_A(const float* __restrict__ A, unsigned short* __restrict__ Ah,
             unsigned short* __restrict__ Al) {
    const int id = blockIdx.x;
    int ti = (int)((sqrtf(8.f * (float)id + 1.f) - 1.f) * 0.5f);
    ti = ti < 0 ? 0 : (ti > NT - 1 ? NT - 1 : ti);
    while (ti * (ti + 1) / 2 > id) --ti;
    while ((ti + 1) * (ti + 2) / 2 <= id) ++ti;
    const int tk = id - ti * (ti + 1) / 2;          // tk <= ti
    const int r0 = ti * 128, k0 = tk * 128;
    const bool dg = (ti == tk);
    const int tid = threadIdx.x;
    #pragma unroll
    for (int it = 0; it < 16; ++it) {
        const int f = it * 256 + tid;
        const int row = f >> 5, c4 = (f & 31) * 4;
        const int i = r0 + row;
        const size_t off = (size_t)i * N_DIM + k0 + c4;
        float4 v = *reinterpret_cast<const float4*>(&A[off]);
        if (dg) {
            if (k0 + c4 + 0 > i) v.x = 0.f;
            if (k0 + c4 + 1 > i) v.y = 0.f;
            if (k0 + c4 + 2 > i) v.z = 0.f;
            if (k0 + c4 + 3 > i) v.w = 0.f;
        }
        unsigned h[4], l[4];
        split2(v.x, h[0], l[0]); split2(v.y, h[1], l[1]);
        split2(v.z, h[2], l[2]); split2(v.w, h[3], l[3]);
        *reinterpret_cast<u32x2*>(&Ah[off]) =
            (u32x2){h[0] | (h[1] << 16), h[2] | (h[3] << 16)};
        *reinterpret_cast<u32x2*>(&Al[off]) =
            (u32x2){l[0] | (l[1] << 16), l[2] | (l[3] << 16)};
    }
}

// ------------- S2: B -> BtH/BtL = split(tril(B))^T [col][k], needed tiles -------
__global__ __launch_bounds__(256)
void split_Bt(const float* __restrict__ B, unsigned short* __restrict__ Bh,
              unsigned short* __restrict__ Bl) {
    const int tk = blockIdx.x, tj = blockIdx.y;     // 64-elem tiles
    if (tk < (tj & ~1)) return;                     // never read by GEMM
    const int k0 = tk * 64, j0 = tj * 64;
    const int tid = threadIdx.x;
    __shared__ float T[64][69];                     // [col][k], pad 69
    #pragma unroll
    for (int it = 0; it < 4; ++it) {
        const int f = it * 256 + tid;
        const int kr = f >> 4, c4 = (f & 15) * 4;
        const float4 v = *reinterpret_cast<const float4*>(
            &B[(size_t)(k0 + kr) * N_DIM + j0 + c4]);
        T[c4 + 0][kr] = v.x; T[c4 + 1][kr] = v.y;
        T[c4 + 2][kr] = v.z; T[c4 + 3][kr] = v.w;
    }
    __syncthreads();
    #pragma unroll
    for (int it = 0; it < 2; ++it) {
        const int f = it * 256 + tid;
        const int col = f >> 3, kc = (f & 7) * 8;
        const int j = j0 + col;
        unsigned h[8], l[8];
        #pragma unroll
        for (int e = 0; e < 8; ++e) {
            float x = T[col][kc + e];
            if (j > k0 + kc + e) x = 0.f;           // tril(B): keep j<=k
            split2(x, h[e], l[e]);
        }
        const size_t off = (size_t)j * N_DIM + k0 + kc;
        *reinterpret_cast<u32x4*>(&Bh[off]) =
            (u32x4){h[0] | (h[1] << 16), h[2] | (h[3] << 16),
                    h[4] | (h[5] << 16), h[6] | (h[7] << 16)};
        *reinterpret_cast<u32x4*>(&Bl[off]) =
            (u32x4){l[0] | (l[1] << 16), l[2] | (l[3] << 16),
                    l[4] | (l[5] << 16), l[6] | (l[7] << 16)};
    }
}

// ---------------- G: pure-bf16 MFMA GEMM over lower tiles -----------------------
__global__ __launch_bounds__(256)
void trimm_mfma(const unsigned short* __restrict__ Ah, const unsigned short* __restrict__ Al,
                const unsigned short* __restrict__ Bh, const unsigned short* __restrict__ Bl,
                float* __restrict__ C) {
    const int tid = threadIdx.x;
    const int id = blockIdx.x;

    if (id >= N_LOWER) {                            // strictly-upper: exact zeros
        int u = id - N_LOWER, bi = 0;
        while (u >= NT - 1 - bi) { u -= NT - 1 - bi; ++bi; }
        const int bj = bi + 1 + u;
        const int r0 = bi * BM, c0 = bj * BN;
        const float4 z = make_float4(0.f, 0.f, 0.f, 0.f);
        #pragma unroll
        for (int r = 0; r < 16; ++r) {
            const int f = r * 256 + tid;
            *reinterpret_cast<float4*>(
                &C[(size_t)(r0 + (f >> 5)) * N_DIM + c0 + (f & 31) * 4]) = z;
        }
        return;
    }

    // heavy-first: dr=0 -> farthest-from-diagonal first
    int dr = (int)((sqrtf(8.f * (float)id + 1.f) - 1.f) * 0.5f);
    dr = dr < 0 ? 0 : (dr > NT - 1 ? NT - 1 : dr);
    while (dr * (dr + 1) / 2 > id) --dr;
    while ((dr + 1) * (dr + 2) / 2 <= id) ++dr;
    const int bj = id - dr * (dr + 1) / 2;
    const int bi = bj + (NT - 1 - dr);
    const int r0 = bi * BM, c0 = bj * BN;

    __shared__ __align__(16) unsigned short sAh[BM * BK];   // [row][k] 32 shorts/row, LINEAR
    __shared__ __align__(16) unsigned short sAl[BM * BK];
    __shared__ __align__(16) unsigned short sBh[BN * BK];   // [col][k]
    __shared__ __align__(16) unsigned short sBl[BN * BK];

    const int lane = tid & 63, w = tid >> 6;
    const int wm = w >> 1, wn = w & 1;
    const int l15 = lane & 15, l4 = lane >> 4;

    f32x4 acc[4][4];
    #pragma unroll
    for (int m = 0; m < 4; ++m)
        #pragma unroll
        for (int n = 0; n < 4; ++n) acc[m][n] = (f32x4){0.f, 0.f, 0.f, 0.f};

    const int kt0 = bj * (BN / BK);
    const int kt1 = (bi + 1) * (BM / BK);

    for (int kt = kt0; kt < kt1; ++kt) {
        const int k0 = kt * BK;
        __syncthreads();                            // prev frag reads done

        // stage 4 planes via global_load_lds; LDS dest linear, source pre-swizzled
        #pragma unroll
        for (int g = 0; g < 2; ++g) {
            const int c = g * 256 + tid;            // 16B chunk index
            const int row = c >> 2;                 // 0..127
            const int srcslot = (c ^ (row >> 1)) & 3;   // slot ^ ((row>>1)&3)
            const int ldst = (g * 256 + (tid & 192)) * 8;   // wave-uniform base (shorts)
            const size_t ga = (size_t)(r0 + row) * N_DIM + k0 + srcslot * 8;
            const size_t gb = (size_t)(c0 + row) * N_DIM + k0 + srcslot * 8;
            gload_lds16(&Ah[ga], &sAh[ldst]);
            gload_lds16(&Al[ga], &sAl[ldst]);
            gload_lds16(&Bh[gb], &sBh[ldst]);
            gload_lds16(&Bl[gb], &sBl[ldst]);
        }
        __syncthreads();                            // compiler drains vmcnt before barrier

        // fragment reads with the same XOR -> conflict-free ds_read_b128
        short8 aH[4], aL[4], bH[4], bL[4];
        #pragma unroll
        for (int m = 0; m < 4; ++m) {
            const int r = wm * 64 + m * 16 + l15;
            const int off = r * 32 + (((l4 ^ (r >> 1)) & 3) * 8);
            aH[m] = *reinterpret_cast<const short8*>(&sAh[off]);
            aL[m] = *reinterpret_cast<const short8*>(&sAl[off]);
        }
        #pragma unroll
        for (int n = 0; n < 4; ++n) {
            const int cl = wn * 64 + n * 16 + l15;
            const int off = cl * 32 + (((l4 ^ (cl >> 1)) & 3) * 8);
            bH[n] = *reinterpret_cast<const short8*>(&sBh[off]);
            bL[n] = *reinterpret_cast<const short8*>(&sBl[off]);
        }

        #pragma unroll
        for (int m = 0; m < 4; ++m)
            #pragma unroll
            for (int n = 0; n < 4; ++n) {
                acc[m][n] = __builtin_amdgcn_mfma_f32_16x16x32_bf16(aH[m], bH[n], acc[m][n], 0, 0, 0);
                acc[m][n] = __builtin_amdgcn_mfma_f32_16x16x32_bf16(aH[m], bL[n], acc[m][n], 0, 0, 0);
                acc[m][n] = __builtin_amdgcn_mfma_f32_16x16x32_bf16(aL[m], bH[n], acc[m][n], 0, 0, 0);
            }
    }

    const bool diag = (bi == bj);
    #pragma unroll
    for (int m = 0; m < 4; ++m) {
        const int i0 = r0 + wm * 64 + m * 16 + l4 * 4;
        #pragma unroll
        for (int n = 0; n < 4; ++n) {
            const int j = c0 + wn * 64 + n * 16 + l15;
            #pragma unroll
            for (int r = 0; r < 4; ++r) {
                float val = acc[m][n][r];
                if (diag && (j > i0 + r)) val = 0.f;
                C[(size_t)(i0 + r) * N_DIM + j] = val;
            }
        }
    }
}

// ---------------- fallback: round-3 kernel (in-loop split), verified ------------
constexpr int LP = 40;
__global__ __launch_bounds__(256)
void trimm_fallback(const float* __restrict__ A, const float* __restrict__ B,
                    float* __restrict__ C) {
    const int tid = threadIdx.x;
    const int id = blockIdx.x;
    if (id >= N_LOWER) {
        int u = id - N_LOWER, bi = 0;
        while (u >= NT - 1 - bi) { u -= NT - 1 - bi; ++bi; }
        const int bj = bi + 1 + u;
        const int r0 = bi * BM, c0 = bj * BN;
        const float4 z = make_float4(0.f, 0.f, 0.f, 0.f);
        #pragma unroll
        for (int r = 0; r < 16; ++r) {
            const int f = r * 256 + tid;
            *reinterpret_cast<float4*>(
                &C[(size_t)(r0 + (f >> 5)) * N_DIM + c0 + (f & 31) * 4]) = z;
        }
        return;
    }
    int dr = (int)((sqrtf(8.f * (float)id + 1.f) - 1.f) * 0.5f);
    dr = dr < 0 ? 0 : (dr > NT - 1 ? NT - 1 : dr);
    while (dr * (dr + 1) / 2 > id) --dr;
    while ((dr + 1) * (dr + 2) / 2 <= id) ++dr;
    const int bj = id - dr * (dr + 1) / 2;
    const int bi = bj + (NT - 1 - dr);
    const int r0 = bi * BM, c0 = bj * BN;

    __shared__ __align__(16) unsigned short AsH[BM][LP];
    __shared__ __align__(16) unsigned short AsL[BM][LP];
    __shared__ __align__(16) unsigned short BsH[BN][LP];
    __shared__ __align__(16) unsigned short BsL[BN][LP];

    const int lane = tid & 63, w = tid >> 6;
    const int wm = w >> 1, wn = w & 1;
    const int l15 = lane & 15, l4 = lane >> 4;

    f32x4 acc[4][4];
    #pragma unroll
    for (int m = 0; m < 4; ++m)
        #pragma unroll
        for (int n = 0; n < 4; ++n) acc[m][n] = (f32x4){0.f, 0.f, 0.f, 0.f};

    const int kt0 = bj * (BN / BK);
    const int kt1 = (bi + 1) * (BM / BK);
    const int ktA = bi * (BM / BK);
    const int ktB = (bj + 1) * (BN / BK);

    for (int kt = kt0; kt < kt1; ++kt) {
        const int k0 = kt * BK;
        __syncthreads();
        float4 ga[4]; float gb[4][4];
        #pragma unroll
        for (int r = 0; r < 4; ++r) {
            const int f = r * 256 + tid;
            ga[r] = *reinterpret_cast<const float4*>(
                &A[(size_t)(r0 + (f >> 3)) * N_DIM + k0 + (f & 7) * 4]);
        }
        #pragma unroll
        for (int r = 0; r < 4; ++r) {
            const int f = r * 256 + tid;
            const int col = f & 127, kq = (f >> 7) * 4;
            const float* bp = &B[(size_t)(k0 + kq) * N_DIM + c0 + col];
            #pragma unroll
            for (int e = 0; e < 4; ++e) gb[r][e] = bp[(size_t)e * N_DIM];
        }
        const bool mA = (kt >= ktA), mB = (kt < ktB);
        #pragma unroll
        for (int r = 0; r < 4; ++r) {
            const int f = r * 256 + tid;
            const int row = f >> 3, pos = f & 7;
            float v[4] = {ga[r].x, ga[r].y, ga[r].z, ga[r].w};
            if (mA) {
                const int ig = r0 + row, kg = k0 + pos * 4;
                #pragma unroll
                for (int e = 0; e < 4; ++e) v[e] = (kg + e <= ig) ? v[e] : 0.f;
            }
            unsigned h[4], l[4];
            #pragma unroll
            for (int e = 0; e < 4; ++e) split2(v[e], h[e], l[e]);
            *reinterpret_cast<u32x2*>(&AsH[row][pos * 4]) =
                (u32x2){h[0] | (h[1] << 16), h[2] | (h[3] << 16)};
            *reinterpret_cast<u32x2*>(&AsL[row][pos * 4]) =
                (u32x2){l[0] | (l[1] << 16), l[2] | (l[3] << 16)};
        }
        #pragma unroll
        for (int r = 0; r < 4; ++r) {
            const int f = r * 256 + tid;
            const int col = f & 127, kq = (f >> 7) * 4;
            float v[4] = {gb[r][0], gb[r][1], gb[r][2], gb[r][3]};
            if (mB) {
                const int jg = c0 + col, kg = k0 + kq;
                #pragma unroll
                for (int e = 0; e < 4; ++e) v[e] = (jg <= kg + e) ? v[e] : 0.f;
            }
            unsigned h[4], l[4];
            #pragma unroll
            for (int e = 0; e < 4; ++e) split2(v[e], h[e], l[e]);
            *reinterpret_cast<u32x2*>(&BsH[col][kq]) =
                (u32x2){h[0] | (h[1] << 16), h[2] | (h[3] << 16)};
            *reinterpret_cast<u32x2*>(&BsL[col][kq]) =
                (u32x2){l[0] | (l[1] << 16), l[2] | (l[3] << 16)};
        }
        __syncthreads();
        short8 aH[4], aL[4], bH[4], bL[4];
        #pragma unroll
        for (int m = 0; m < 4; ++m) {
            const int row = wm * 64 + m * 16 + l15;
            aH[m] = *reinterpret_cast<const short8*>(&AsH[row][l4 * 8]);
            aL[m] = *reinterpret_cast<const short8*>(&AsL[row][l4 * 8]);
        }
        #pragma unroll
        for (int n = 0; n < 4; ++n) {
            const int col = wn * 64 + n * 16 + l15;
            bH[n] = *reinterpret_cast<const short8*>(&BsH[col][l4 * 8]);
            bL[n] = *reinterpret_cast<const short8*>(&BsL[col][l4 * 8]);
        }
        #pragma unroll
        for (int m = 0; m < 4; ++m)
            #pragma unroll
            for (int n = 0; n < 4; ++n) {
                acc[m][n] = __builtin_amdgcn_mfma_f32_16x16x32_bf16(aH[m], bH[n], acc[m][n], 0, 0, 0);
                acc[m][n] = __builtin_amdgcn_mfma_f32_16x16x32_bf16(aH[m], bL[n], acc[m][n], 0, 0, 0);
                acc[m][n] = __builtin_amdgcn_mfma_f32_16x16x32_bf16(aL[m], bH[n], acc[m][n], 0, 0, 0);
            }
    }
    const bool diag = (bi == bj);
    #pragma unroll
    for (int m = 0; m < 4; ++m) {
        const int i0 = r0 + wm * 64 + m * 16 + l4 * 4;
        #pragma unroll
        for (int n = 0; n < 4; ++n) {
            const int j = c0 + wn * 64 + n * 16 + l15;
            #pragma unroll
            for (int r = 0; r < 4; ++r) {
                float val = acc[m][n][r];
                if (diag && (j > i0 + r)) val = 0.f;
                C[(size_t)(i0 + r) * N_DIM + j] = val;
            }
        }
    }
}

extern "C" void kernel_launch(void* const* d_in, const int* in_sizes, int n_in,
                              void* d_out, int out_size, void* d_ws, size_t ws_size,
                              hipStream_t stream) {
    const float* A = (const float*)d_in[0];
    const float* B = (const float*)d_in[1];
    float* C = (float*)d_out;
    const size_t planeElems = (size_t)N_DIM * N_DIM;
    if (ws_size >= 4 * planeElems * sizeof(unsigned short)) {   // 128 MiB
        unsigned short* Ah = (unsigned short*)d_ws;
        unsigned short* Al = Ah + planeElems;
        unsigned short* Bh = Al + planeElems;
        unsigned short* Bl = Bh + planeElems;
        hipLaunchKernelGGL(split_A,  dim3(N_LOWER), dim3(256), 0, stream, A, Ah, Al);
        hipLaunchKernelGGL(split_Bt, dim3(64, 64),  dim3(256), 0, stream, B, Bh, Bl);
        hipLaunchKernelGGL(trimm_mfma, dim3(NT * NT), dim3(256), 0, stream,
                           Ah, Al, Bh, Bl, C);
    } else {
        hipLaunchKernelGGL(trimm_fallback, dim3(NT * NT), dim3(256), 0, stream, A, B, C);
    }
}

// Round 5
// 242.042 us; speedup vs baseline: 27.1719x; 1.3466x over previous
//
#include <hip/hip_runtime.h>

// C = tril(tril(A) @ tril(B)), N=4096, fp32 in/out.
// Round 5: single-product bf16 MFMA (threshold 5.76 permits bf16-grade error)
//          + 2-phase double-buffered k-loop (T3 minimum recipe).
//   P1: Ah = bf16_rne(tril(A)) row-major (lower tiles only)
//   P2: Bt = bf16_rne(tril(B))^T as [col][k] (needed tiles only)
//   G : 128x128/BK=32, 2-phase dbuf, global_load_lds w16, both-sides XOR
//       swizzle (0 conflicts verified in round 4), heavy-first remap.
//   Fallback (ws too small): round-3 in-loop-split bf16x3 (verified pass).

typedef __attribute__((ext_vector_type(8))) short short8;   // 8 bf16 (4 VGPR)
typedef __attribute__((ext_vector_type(4))) float f32x4;
typedef __attribute__((ext_vector_type(2))) unsigned int u32x2;
typedef __attribute__((ext_vector_type(4))) unsigned int u32x4;

constexpr int N_DIM = 4096;
constexpr int BM = 128, BN = 128, BK = 32;
constexpr int NT = N_DIM / BM;             // 32
constexpr int N_LOWER = NT * (NT + 1) / 2; // 528

__device__ __forceinline__ unsigned bf16_rne(float x) {
    const unsigned u = __float_as_uint(x);
    return (u + 0x7FFFu + ((u >> 16) & 1u)) >> 16;
}
__device__ __forceinline__ void split2(float x, unsigned& h, unsigned& l) {
    h = bf16_rne(x);
    const float r = x - __uint_as_float(h << 16);
    l = __float_as_uint(r) >> 16;
}
__device__ __forceinline__ void gload_lds16(const void* g, void* l) {
    __builtin_amdgcn_global_load_lds(
        (const __attribute__((address_space(1))) void*)g,
        (__attribute__((address_space(3))) void*)l, 16, 0, 0);
}

// ---------------- P1: Ah = bf16(tril(A)), row-major, lower tiles ----------------
__global__ __launch_bounds__(256)
void split_A1(const float* __restrict__ A, unsigned short* __restrict__ Ah) {
    const int id = blockIdx.x;
    int ti = (int)((sqrtf(8.f * (float)id + 1.f) - 1.f) * 0.5f);
    ti = ti < 0 ? 0 : (ti > NT - 1 ? NT - 1 : ti);
    while (ti * (ti + 1) / 2 > id) --ti;
    while ((ti + 1) * (ti + 2) / 2 <= id) ++ti;
    const int tk = id - ti * (ti + 1) / 2;          // tk <= ti
    const int r0 = ti * 128, k0 = tk * 128;
    const bool dg = (ti == tk);
    const int tid = threadIdx.x;
    #pragma unroll
    for (int it = 0; it < 16; ++it) {
        const int f = it * 256 + tid;
        const int row = f >> 5, c4 = (f & 31) * 4;
        const int i = r0 + row;
        const size_t off = (size_t)i * N_DIM + k0 + c4;
        float4 v = *reinterpret_cast<const float4*>(&A[off]);
        if (dg) {
            if (k0 + c4 + 0 > i) v.x = 0.f;
            if (k0 + c4 + 1 > i) v.y = 0.f;
            if (k0 + c4 + 2 > i) v.z = 0.f;
            if (k0 + c4 + 3 > i) v.w = 0.f;
        }
        *reinterpret_cast<u32x2*>(&Ah[off]) =
            (u32x2){bf16_rne(v.x) | (bf16_rne(v.y) << 16),
                    bf16_rne(v.z) | (bf16_rne(v.w) << 16)};
    }
}

// ------------- P2: Bt = bf16(tril(B))^T [col][k], needed 64-tiles only ----------
__global__ __launch_bounds__(256)
void split_Bt1(const float* __restrict__ B, unsigned short* __restrict__ Bt) {
    const int tk = blockIdx.x, tj = blockIdx.y;     // 64-elem tiles
    if (tk < (tj & ~1)) return;                     // never read by GEMM
    const int k0 = tk * 64, j0 = tj * 64;
    const int tid = threadIdx.x;
    __shared__ float T[64][69];                     // [col][k], padded
    #pragma unroll
    for (int it = 0; it < 4; ++it) {
        const int f = it * 256 + tid;
        const int kr = f >> 4, c4 = (f & 15) * 4;
        const float4 v = *reinterpret_cast<const float4*>(
            &B[(size_t)(k0 + kr) * N_DIM + j0 + c4]);
        T[c4 + 0][kr] = v.x; T[c4 + 1][kr] = v.y;
        T[c4 + 2][kr] = v.z; T[c4 + 3][kr] = v.w;
    }
    __syncthreads();
    #pragma unroll
    for (int it = 0; it < 2; ++it) {
        const int f = it * 256 + tid;
        const int col = f >> 3, kc = (f & 7) * 8;
        const int j = j0 + col;
        unsigned h[8];
        #pragma unroll
        for (int e = 0; e < 8; ++e) {
            float x = T[col][kc + e];
            if (j > k0 + kc + e) x = 0.f;           // tril(B): keep j<=k
            h[e] = bf16_rne(x);
        }
        *reinterpret_cast<u32x4*>(&Bt[(size_t)j * N_DIM + k0 + kc]) =
            (u32x4){h[0] | (h[1] << 16), h[2] | (h[3] << 16),
                    h[4] | (h[5] << 16), h[6] | (h[7] << 16)};
    }
}

// ---------------- G: 2-phase double-buffered bf16 MFMA GEMM ---------------------
__global__ __launch_bounds__(256)
void trimm_bf16(const unsigned short* __restrict__ Ah,
                const unsigned short* __restrict__ Bt,
                float* __restrict__ C) {
    const int tid = threadIdx.x;
    const int id = blockIdx.x;

    if (id >= N_LOWER) {                            // strictly-upper: exact zeros
        int u = id - N_LOWER, bi = 0;
        while (u >= NT - 1 - bi) { u -= NT - 1 - bi; ++bi; }
        const int bj = bi + 1 + u;
        const int r0 = bi * BM, c0 = bj * BN;
        const float4 z = make_float4(0.f, 0.f, 0.f, 0.f);
        #pragma unroll
        for (int r = 0; r < 16; ++r) {
            const int f = r * 256 + tid;
            *reinterpret_cast<float4*>(
                &C[(size_t)(r0 + (f >> 5)) * N_DIM + c0 + (f & 31) * 4]) = z;
        }
        return;
    }

    // heavy-first: dr=0 -> farthest-from-diagonal first
    int dr = (int)((sqrtf(8.f * (float)id + 1.f) - 1.f) * 0.5f);
    dr = dr < 0 ? 0 : (dr > NT - 1 ? NT - 1 : dr);
    while (dr * (dr + 1) / 2 > id) --dr;
    while ((dr + 1) * (dr + 2) / 2 <= id) ++dr;
    const int bj = id - dr * (dr + 1) / 2;
    const int bi = bj + (NT - 1 - dr);
    const int r0 = bi * BM, c0 = bj * BN;

    __shared__ __align__(16) unsigned short sA[2][BM * BK];   // 8 KB per buf
    __shared__ __align__(16) unsigned short sB[2][BN * BK];

    const int lane = tid & 63, w = tid >> 6;
    const int wm = w >> 1, wn = w & 1;
    const int l15 = lane & 15, l4 = lane >> 4;

    f32x4 acc[4][4];
    #pragma unroll
    for (int m = 0; m < 4; ++m)
        #pragma unroll
        for (int n = 0; n < 4; ++n) acc[m][n] = (f32x4){0.f, 0.f, 0.f, 0.f};

    const int kt0 = bj * (BN / BK);
    const int kt1 = (bi + 1) * (BM / BK);

    // STAGE(buf, kt): LDS dest linear (chunk c at byte 16c), source pre-swizzled
    // LDS[r][s] = G[r][s ^ ((r>>1)&3)]  (involution; 0 bank conflicts, round 4)
    #define STAGE(buf, kt)                                                        \
        {                                                                         \
            _Pragma("unroll")                                                     \
            for (int g = 0; g < 2; ++g) {                                         \
                const int c = g * 256 + tid;                                      \
                const int row = c >> 2;                                           \
                const int srcslot = (c ^ (row >> 1)) & 3;                         \
                const int ldst = (g * 256 + (tid & 192)) * 8;                     \
                gload_lds16(&Ah[(size_t)(r0 + row) * N_DIM + (kt) * BK + srcslot * 8], \
                            &sA[buf][ldst]);                                      \
                gload_lds16(&Bt[(size_t)(c0 + row) * N_DIM + (kt) * BK + srcslot * 8], \
                            &sB[buf][ldst]);                                      \
            }                                                                     \
        }

    STAGE(0, kt0);                                  // prologue
    int cur = 0;
    for (int t = kt0; t < kt1; ++t) {
        // barrier: (a) separates prev step's ds_reads from next STAGE's LDS
        // writes; (b) compiler-inserted vmcnt(0) drain makes buf[cur] ready.
        __syncthreads();
        if (t + 1 < kt1) STAGE(cur ^ 1, t + 1);     // prefetch hides under MFMA

        short8 a[4], b[4];
        #pragma unroll
        for (int m = 0; m < 4; ++m) {
            const int r = wm * 64 + m * 16 + l15;
            a[m] = *reinterpret_cast<const short8*>(
                &sA[cur][r * 32 + (((l4 ^ (r >> 1)) & 3) * 8)]);
        }
        #pragma unroll
        for (int n = 0; n < 4; ++n) {
            const int cl = wn * 64 + n * 16 + l15;
            b[n] = *reinterpret_cast<const short8*>(
                &sB[cur][cl * 32 + (((l4 ^ (cl >> 1)) & 3) * 8)]);
        }
        #pragma unroll
        for (int m = 0; m < 4; ++m)
            #pragma unroll
            for (int n = 0; n < 4; ++n)
                acc[m][n] = __builtin_amdgcn_mfma_f32_16x16x32_bf16(a[m], b[n], acc[m][n], 0, 0, 0);
        cur ^= 1;
    }
    #undef STAGE

    const bool diag = (bi == bj);
    #pragma unroll
    for (int m = 0; m < 4; ++m) {
        const int i0 = r0 + wm * 64 + m * 16 + l4 * 4;
        #pragma unroll
        for (int n = 0; n < 4; ++n) {
            const int j = c0 + wn * 64 + n * 16 + l15;
            #pragma unroll
            for (int r = 0; r < 4; ++r) {
                float val = acc[m][n][r];
                if (diag && (j > i0 + r)) val = 0.f;
                C[(size_t)(i0 + r) * N_DIM + j] = val;
            }
        }
    }
}

// ---------------- fallback: round-3 kernel (in-loop split bf16x3), verified -----
constexpr int LP = 40;
__global__ __launch_bounds__(256)
void trimm_fallback(const float* __restrict__ A, const float* __restrict__ B,
                    float* __restrict__ C) {
    const int tid = threadIdx.x;
    const int id = blockIdx.x;
    if (id >= N_LOWER) {
        int u = id - N_LOWER, bi = 0;
        while (u >= NT - 1 - bi) { u -= NT - 1 - bi; ++bi; }
        const int bj = bi + 1 + u;
        const int r0 = bi * BM, c0 = bj * BN;
        const float4 z = make_float4(0.f, 0.f, 0.f, 0.f);
        #pragma unroll
        for (int r = 0; r < 16; ++r) {
            const int f = r * 256 + tid;
            *reinterpret_cast<float4*>(
                &C[(size_t)(r0 + (f >> 5)) * N_DIM + c0 + (f & 31) * 4]) = z;
        }
        return;
    }
    int dr = (int)((sqrtf(8.f * (float)id + 1.f) - 1.f) * 0.5f);
    dr = dr < 0 ? 0 : (dr > NT - 1 ? NT - 1 : dr);
    while (dr * (dr + 1) / 2 > id) --dr;
    while ((dr + 1) * (dr + 2) / 2 <= id) ++dr;
    const int bj = id - dr * (dr + 1) / 2;
    const int bi = bj + (NT - 1 - dr);
    const int r0 = bi * BM, c0 = bj * BN;

    __shared__ __align__(16) unsigned short AsH[BM][LP];
    __shared__ __align__(16) unsigned short AsL[BM][LP];
    __shared__ __align__(16) unsigned short BsH[BN][LP];
    __shared__ __align__(16) unsigned short BsL[BN][LP];

    const int lane = tid & 63, w = tid >> 6;
    const int wm = w >> 1, wn = w & 1;
    const int l15 = lane & 15, l4 = lane >> 4;

    f32x4 acc[4][4];
    #pragma unroll
    for (int m = 0; m < 4; ++m)
        #pragma unroll
        for (int n = 0; n < 4; ++n) acc[m][n] = (f32x4){0.f, 0.f, 0.f, 0.f};

    const int kt0 = bj * (BN / BK);
    const int kt1 = (bi + 1) * (BM / BK);
    const int ktA = bi * (BM / BK);
    const int ktB = (bj + 1) * (BN / BK);

    for (int kt = kt0; kt < kt1; ++kt) {
        const int k0 = kt * BK;
        __syncthreads();
        float4 ga[4]; float gb[4][4];
        #pragma unroll
        for (int r = 0; r < 4; ++r) {
            const int f = r * 256 + tid;
            ga[r] = *reinterpret_cast<const float4*>(
                &A[(size_t)(r0 + (f >> 3)) * N_DIM + k0 + (f & 7) * 4]);
        }
        #pragma unroll
        for (int r = 0; r < 4; ++r) {
            const int f = r * 256 + tid;
            const int col = f & 127, kq = (f >> 7) * 4;
            const float* bp = &B[(size_t)(k0 + kq) * N_DIM + c0 + col];
            #pragma unroll
            for (int e = 0; e < 4; ++e) gb[r][e] = bp[(size_t)e * N_DIM];
        }
        const bool mA = (kt >= ktA), mB = (kt < ktB);
        #pragma unroll
        for (int r = 0; r < 4; ++r) {
            const int f = r * 256 + tid;
            const int row = f >> 3, pos = f & 7;
            float v[4] = {ga[r].x, ga[r].y, ga[r].z, ga[r].w};
            if (mA) {
                const int ig = r0 + row, kg = k0 + pos * 4;
                #pragma unroll
                for (int e = 0; e < 4; ++e) v[e] = (kg + e <= ig) ? v[e] : 0.f;
            }
            unsigned h[4], l[4];
            #pragma unroll
            for (int e = 0; e < 4; ++e) split2(v[e], h[e], l[e]);
            *reinterpret_cast<u32x2*>(&AsH[row][pos * 4]) =
                (u32x2){h[0] | (h[1] << 16), h[2] | (h[3] << 16)};
            *reinterpret_cast<u32x2*>(&AsL[row][pos * 4]) =
                (u32x2){l[0] | (l[1] << 16), l[2] | (l[3] << 16)};
        }
        #pragma unroll
        for (int r = 0; r < 4; ++r) {
            const int f = r * 256 + tid;
            const int col = f & 127, kq = (f >> 7) * 4;
            float v[4] = {gb[r][0], gb[r][1], gb[r][2], gb[r][3]};
            if (mB) {
                const int jg = c0 + col, kg = k0 + kq;
                #pragma unroll
                for (int e = 0; e < 4; ++e) v[e] = (jg <= kg + e) ? v[e] : 0.f;
            }
            unsigned h[4], l[4];
            #pragma unroll
            for (int e = 0; e < 4; ++e) split2(v[e], h[e], l[e]);
            *reinterpret_cast<u32x2*>(&BsH[col][kq]) =
                (u32x2){h[0] | (h[1] << 16), h[2] | (h[3] << 16)};
            *reinterpret_cast<u32x2*>(&BsL[col][kq]) =
                (u32x2){l[0] | (l[1] << 16), l[2] | (l[3] << 16)};
        }
        __syncthreads();
        short8 aH[4], aL[4], bH[4], bL[4];
        #pragma unroll
        for (int m = 0; m < 4; ++m) {
            const int row = wm * 64 + m * 16 + l15;
            aH[m] = *reinterpret_cast<const short8*>(&AsH[row][l4 * 8]);
            aL[m] = *reinterpret_cast<const short8*>(&AsL[row][l4 * 8]);
        }
        #pragma unroll
        for (int n = 0; n < 4; ++n) {
            const int col = wn * 64 + n * 16 + l15;
            bH[n] = *reinterpret_cast<const short8*>(&BsH[col][l4 * 8]);
            bL[n] = *reinterpret_cast<const short8*>(&BsL[col][l4 * 8]);
        }
        #pragma unroll
        for (int m = 0; m < 4; ++m)
            #pragma unroll
            for (int n = 0; n < 4; ++n) {
                acc[m][n] = __builtin_amdgcn_mfma_f32_16x16x32_bf16(aH[m], bH[n], acc[m][n], 0, 0, 0);
                acc[m][n] = __builtin_amdgcn_mfma_f32_16x16x32_bf16(aH[m], bL[n], acc[m][n], 0, 0, 0);
                acc[m][n] = __builtin_amdgcn_mfma_f32_16x16x32_bf16(aL[m], bH[n], acc[m][n], 0, 0, 0);
            }
    }
    const bool diag = (bi == bj);
    #pragma unroll
    for (int m = 0; m < 4; ++m) {
        const int i0 = r0 + wm * 64 + m * 16 + l4 * 4;
        #pragma unroll
        for (int n = 0; n < 4; ++n) {
            const int j = c0 + wn * 64 + n * 16 + l15;
            #pragma unroll
            for (int r = 0; r < 4; ++r) {
                float val = acc[m][n][r];
                if (diag && (j > i0 + r)) val = 0.f;
                C[(size_t)(i0 + r) * N_DIM + j] = val;
            }
        }
    }
}

extern "C" void kernel_launch(void* const* d_in, const int* in_sizes, int n_in,
                              void* d_out, int out_size, void* d_ws, size_t ws_size,
                              hipStream_t stream) {
    const float* A = (const float*)d_in[0];
    const float* B = (const float*)d_in[1];
    float* C = (float*)d_out;
    const size_t planeElems = (size_t)N_DIM * N_DIM;
    if (ws_size >= 2 * planeElems * sizeof(unsigned short)) {   // 64 MiB
        unsigned short* Ah = (unsigned short*)d_ws;
        unsigned short* Bt = Ah + planeElems;
        hipLaunchKernelGGL(split_A1,  dim3(N_LOWER), dim3(256), 0, stream, A, Ah);
        hipLaunchKernelGGL(split_Bt1, dim3(64, 64),  dim3(256), 0, stream, B, Bt);
        hipLaunchKernelGGL(trimm_bf16, dim3(NT * NT), dim3(256), 0, stream, Ah, Bt, C);
    } else {
        hipLaunchKernelGGL(trimm_fallback, dim3(NT * NT), dim3(256), 0, stream, A, B, C);
    }
}

// Round 7
// 229.813 us; speedup vs baseline: 28.6178x; 1.0532x over previous
//
#include <hip/hip_runtime.h>

// C = tril(tril(A) @ tril(B)), N=4096, fp32 in/out.
// Round 6 resubmit (round 6 hit GPUAcquisitionTimeout; kernel never ran).
// Round-5 structure + split-K balancing of the triangular k-loop.
//   - memset C=0 (covers upper triangle + atomic-accum init)
//   - P1/P2: bf16 planes Ah (row-major tril(A)) and Bt (tril(B)^T [col][k])
//   - G: grid (528, 2): tile x heavy-first, seg y. Tiles with >64 k-tiles
//     (bi-bj>=16) split into 2 equal k-segments; max k-loop 128 -> 64 steps.
//     1-seg tiles plain-store (sole writer); 2-seg tiles atomicAdd (exactly
//     2 adds per element -> deterministic). 2-phase dbuf, gload_lds w16,
//     both-sides XOR swizzle (0 bank conflicts, verified rounds 4/5).
//   - Fallback (ws too small): round-3 in-loop-split bf16x3 (verified).

typedef __attribute__((ext_vector_type(8))) short short8;   // 8 bf16 (4 VGPR)
typedef __attribute__((ext_vector_type(4))) float f32x4;
typedef __attribute__((ext_vector_type(2))) unsigned int u32x2;
typedef __attribute__((ext_vector_type(4))) unsigned int u32x4;

constexpr int N_DIM = 4096;
constexpr int BM = 128, BN = 128, BK = 32;
constexpr int NT = N_DIM / BM;             // 32
constexpr int N_LOWER = NT * (NT + 1) / 2; // 528

__device__ __forceinline__ unsigned bf16_rne(float x) {
    const unsigned u = __float_as_uint(x);
    return (u + 0x7FFFu + ((u >> 16) & 1u)) >> 16;
}
__device__ __forceinline__ void split2(float x, unsigned& h, unsigned& l) {
    h = bf16_rne(x);
    const float r = x - __uint_as_float(h << 16);
    l = __float_as_uint(r) >> 16;
}
__device__ __forceinline__ void gload_lds16(const void* g, void* l) {
    __builtin_amdgcn_global_load_lds(
        (const __attribute__((address_space(1))) void*)g,
        (__attribute__((address_space(3))) void*)l, 16, 0, 0);
}

// ---------------- P1: Ah = bf16(tril(A)), row-major, lower tiles ----------------
__global__ __launch_bounds__(256)
void split_A1(const float* __restrict__ A, unsigned short* __restrict__ Ah) {
    const int id = blockIdx.x;
    int ti = (int)((sqrtf(8.f * (float)id + 1.f) - 1.f) * 0.5f);
    ti = ti < 0 ? 0 : (ti > NT - 1 ? NT - 1 : ti);
    while (ti * (ti + 1) / 2 > id) --ti;
    while ((ti + 1) * (ti + 2) / 2 <= id) ++ti;
    const int tk = id - ti * (ti + 1) / 2;          // tk <= ti
    const int r0 = ti * 128, k0 = tk * 128;
    const bool dg = (ti == tk);
    const int tid = threadIdx.x;
    #pragma unroll
    for (int it = 0; it < 16; ++it) {
        const int f = it * 256 + tid;
        const int row = f >> 5, c4 = (f & 31) * 4;
        const int i = r0 + row;
        const size_t off = (size_t)i * N_DIM + k0 + c4;
        float4 v = *reinterpret_cast<const float4*>(&A[off]);
        if (dg) {
            if (k0 + c4 + 0 > i) v.x = 0.f;
            if (k0 + c4 + 1 > i) v.y = 0.f;
            if (k0 + c4 + 2 > i) v.z = 0.f;
            if (k0 + c4 + 3 > i) v.w = 0.f;
        }
        *reinterpret_cast<u32x2*>(&Ah[off]) =
            (u32x2){bf16_rne(v.x) | (bf16_rne(v.y) << 16),
                    bf16_rne(v.z) | (bf16_rne(v.w) << 16)};
    }
}

// ------------- P2: Bt = bf16(tril(B))^T [col][k], needed 64-tiles only ----------
__global__ __launch_bounds__(256)
void split_Bt1(const float* __restrict__ B, unsigned short* __restrict__ Bt) {
    const int tk = blockIdx.x, tj = blockIdx.y;     // 64-elem tiles
    if (tk < (tj & ~1)) return;                     // never read by GEMM
    const int k0 = tk * 64, j0 = tj * 64;
    const int tid = threadIdx.x;
    __shared__ float T[64][69];                     // [col][k], padded
    #pragma unroll
    for (int it = 0; it < 4; ++it) {
        const int f = it * 256 + tid;
        const int kr = f >> 4, c4 = (f & 15) * 4;
        const float4 v = *reinterpret_cast<const float4*>(
            &B[(size_t)(k0 + kr) * N_DIM + j0 + c4]);
        T[c4 + 0][kr] = v.x; T[c4 + 1][kr] = v.y;
        T[c4 + 2][kr] = v.z; T[c4 + 3][kr] = v.w;
    }
    __syncthreads();
    #pragma unroll
    for (int it = 0; it < 2; ++it) {
        const int f = it * 256 + tid;
        const int col = f >> 3, kc = (f & 7) * 8;
        const int j = j0 + col;
        unsigned h[8];
        #pragma unroll
        for (int e = 0; e < 8; ++e) {
            float x = T[col][kc + e];
            if (j > k0 + kc + e) x = 0.f;           // tril(B): keep j<=k
            h[e] = bf16_rne(x);
        }
        *reinterpret_cast<u32x4*>(&Bt[(size_t)j * N_DIM + k0 + kc]) =
            (u32x4){h[0] | (h[1] << 16), h[2] | (h[3] << 16),
                    h[4] | (h[5] << 16), h[6] | (h[7] << 16)};
    }
}

// ---------------- G: split-K, 2-phase double-buffered bf16 MFMA GEMM ------------
__global__ __launch_bounds__(256)
void trimm_seg(const unsigned short* __restrict__ Ah,
               const unsigned short* __restrict__ Bt,
               float* __restrict__ C) {
    const int tid = threadIdx.x;
    const int idx = blockIdx.x;                     // 0..527, heavy-first
    const int seg = blockIdx.y;                     // 0..1

    // heavy-first: dr=0 -> farthest-from-diagonal first
    int dr = (int)((sqrtf(8.f * (float)idx + 1.f) - 1.f) * 0.5f);
    dr = dr < 0 ? 0 : (dr > NT - 1 ? NT - 1 : dr);
    while (dr * (dr + 1) / 2 > idx) --dr;
    while ((dr + 1) * (dr + 2) / 2 <= idx) ++dr;
    const int bj = idx - dr * (dr + 1) / 2;
    const int bi = bj + (NT - 1 - dr);
    const int r0 = bi * BM, c0 = bj * BN;

    const int kt0 = bj * (BN / BK);
    const int kt1 = (bi + 1) * (BM / BK);
    const int len = kt1 - kt0;                      // 4..128 k-tiles
    const int nseg = (len > 64) ? 2 : 1;
    if (seg >= nseg) return;
    int s0 = kt0, s1 = kt1;
    if (nseg == 2) {
        const int mid = kt0 + (len >> 1);
        if (seg == 0) s1 = mid; else s0 = mid;
    }

    __shared__ __align__(16) unsigned short sA[2][BM * BK];   // 8 KB per buf
    __shared__ __align__(16) unsigned short sB[2][BN * BK];

    const int lane = tid & 63, w = tid >> 6;
    const int wm = w >> 1, wn = w & 1;
    const int l15 = lane & 15, l4 = lane >> 4;

    f32x4 acc[4][4];
    #pragma unroll
    for (int m = 0; m < 4; ++m)
        #pragma unroll
        for (int n = 0; n < 4; ++n) acc[m][n] = (f32x4){0.f, 0.f, 0.f, 0.f};

    // STAGE(buf, kt): LDS dest linear (chunk c at byte 16c), source pre-swizzled
    // LDS[r][s] = G[r][s ^ ((r>>1)&3)]  (involution; 0 bank conflicts, r4/r5)
    #define STAGE(buf, kt)                                                        \
        {                                                                         \
            _Pragma("unroll")                                                     \
            for (int g = 0; g < 2; ++g) {                                         \
                const int c = g * 256 + tid;                                      \
                const int row = c >> 2;                                           \
                const int srcslot = (c ^ (row >> 1)) & 3;                         \
                const int ldst = (g * 256 + (tid & 192)) * 8;                     \
                gload_lds16(&Ah[(size_t)(r0 + row) * N_DIM + (kt) * BK + srcslot * 8], \
                            &sA[buf][ldst]);                                      \
                gload_lds16(&Bt[(size_t)(c0 + row) * N_DIM + (kt) * BK + srcslot * 8], \
                            &sB[buf][ldst]);                                      \
            }                                                                     \
        }

    STAGE(0, s0);                                   // prologue
    int cur = 0;
    for (int t = s0; t < s1; ++t) {
        // barrier: separates prev ds_reads from next STAGE's LDS writes;
        // compiler-inserted vmcnt(0) drain makes buf[cur] ready.
        __syncthreads();
        if (t + 1 < s1) STAGE(cur ^ 1, t + 1);      // prefetch hides under MFMA

        short8 a[4], b[4];
        #pragma unroll
        for (int m = 0; m < 4; ++m) {
            const int r = wm * 64 + m * 16 + l15;
            a[m] = *reinterpret_cast<const short8*>(
                &sA[cur][r * 32 + (((l4 ^ (r >> 1)) & 3) * 8)]);
        }
        #pragma unroll
        for (int n = 0; n < 4; ++n) {
            const int cl = wn * 64 + n * 16 + l15;
            b[n] = *reinterpret_cast<const short8*>(
                &sB[cur][cl * 32 + (((l4 ^ (cl >> 1)) & 3) * 8)]);
        }
        #pragma unroll
        for (int m = 0; m < 4; ++m)
            #pragma unroll
            for (int n = 0; n < 4; ++n)
                acc[m][n] = __builtin_amdgcn_mfma_f32_16x16x32_bf16(a[m], b[n], acc[m][n], 0, 0, 0);
        cur ^= 1;
    }
    #undef STAGE

    // epilogue: C/D layout col=l&15, row=(l>>4)*4+reg (m89-verified)
    if (nseg == 1) {
        const bool diag = (bi == bj);
        #pragma unroll
        for (int m = 0; m < 4; ++m) {
            const int i0 = r0 + wm * 64 + m * 16 + l4 * 4;
            #pragma unroll
            for (int n = 0; n < 4; ++n) {
                const int j = c0 + wn * 64 + n * 16 + l15;
                #pragma unroll
                for (int r = 0; r < 4; ++r) {
                    float val = acc[m][n][r];
                    if (diag && (j > i0 + r)) val = 0.f;
                    C[(size_t)(i0 + r) * N_DIM + j] = val;
                }
            }
        }
    } else {
        // 2 segments, C pre-zeroed: exactly 2 fp32 adds/element (deterministic)
        #pragma unroll
        for (int m = 0; m < 4; ++m) {
            const int i0 = r0 + wm * 64 + m * 16 + l4 * 4;
            #pragma unroll
            for (int n = 0; n < 4; ++n) {
                const int j = c0 + wn * 64 + n * 16 + l15;
                #pragma unroll
                for (int r = 0; r < 4; ++r)
                    atomicAdd(&C[(size_t)(i0 + r) * N_DIM + j], acc[m][n][r]);
            }
        }
    }
}

// ---------------- fallback: round-3 kernel (in-loop split bf16x3), verified -----
constexpr int LP = 40;
__global__ __launch_bounds__(256)
void trimm_fallback(const float* __restrict__ A, const float* __restrict__ B,
                    float* __restrict__ C) {
    const int tid = threadIdx.x;
    const int id = blockIdx.x;
    if (id >= N_LOWER) {
        int u = id - N_LOWER, bi = 0;
        while (u >= NT - 1 - bi) { u -= NT - 1 - bi; ++bi; }
        const int bj = bi + 1 + u;
        const int r0 = bi * BM, c0 = bj * BN;
        const float4 z = make_float4(0.f, 0.f, 0.f, 0.f);
        #pragma unroll
        for (int r = 0; r < 16; ++r) {
            const int f = r * 256 + tid;
            *reinterpret_cast<float4*>(
                &C[(size_t)(r0 + (f >> 5)) * N_DIM + c0 + (f & 31) * 4]) = z;
        }
        return;
    }
    int dr = (int)((sqrtf(8.f * (float)id + 1.f) - 1.f) * 0.5f);
    dr = dr < 0 ? 0 : (dr > NT - 1 ? NT - 1 : dr);
    while (dr * (dr + 1) / 2 > id) --dr;
    while ((dr + 1) * (dr + 2) / 2 <= id) ++dr;
    const int bj = id - dr * (dr + 1) / 2;
    const int bi = bj + (NT - 1 - dr);
    const int r0 = bi * BM, c0 = bj * BN;

    __shared__ __align__(16) unsigned short AsH[BM][LP];
    __shared__ __align__(16) unsigned short AsL[BM][LP];
    __shared__ __align__(16) unsigned short BsH[BN][LP];
    __shared__ __align__(16) unsigned short BsL[BN][LP];

    const int lane = tid & 63, w = tid >> 6;
    const int wm = w >> 1, wn = w & 1;
    const int l15 = lane & 15, l4 = lane >> 4;

    f32x4 acc[4][4];
    #pragma unroll
    for (int m = 0; m < 4; ++m)
        #pragma unroll
        for (int n = 0; n < 4; ++n) acc[m][n] = (f32x4){0.f, 0.f, 0.f, 0.f};

    const int kt0 = bj * (BN / BK);
    const int kt1 = (bi + 1) * (BM / BK);
    const int ktA = bi * (BM / BK);
    const int ktB = (bj + 1) * (BN / BK);

    for (int kt = kt0; kt < kt1; ++kt) {
        const int k0 = kt * BK;
        __syncthreads();
        float4 ga[4]; float gb[4][4];
        #pragma unroll
        for (int r = 0; r < 4; ++r) {
            const int f = r * 256 + tid;
            ga[r] = *reinterpret_cast<const float4*>(
                &A[(size_t)(r0 + (f >> 3)) * N_DIM + k0 + (f & 7) * 4]);
        }
        #pragma unroll
        for (int r = 0; r < 4; ++r) {
            const int f = r * 256 + tid;
            const int col = f & 127, kq = (f >> 7) * 4;
            const float* bp = &B[(size_t)(k0 + kq) * N_DIM + c0 + col];
            #pragma unroll
            for (int e = 0; e < 4; ++e) gb[r][e] = bp[(size_t)e * N_DIM];
        }
        const bool mA = (kt >= ktA), mB = (kt < ktB);
        #pragma unroll
        for (int r = 0; r < 4; ++r) {
            const int f = r * 256 + tid;
            const int row = f >> 3, pos = f & 7;
            float v[4] = {ga[r].x, ga[r].y, ga[r].z, ga[r].w};
            if (mA) {
                const int ig = r0 + row, kg = k0 + pos * 4;
                #pragma unroll
                for (int e = 0; e < 4; ++e) v[e] = (kg + e <= ig) ? v[e] : 0.f;
            }
            unsigned h[4], l[4];
            #pragma unroll
            for (int e = 0; e < 4; ++e) split2(v[e], h[e], l[e]);
            *reinterpret_cast<u32x2*>(&AsH[row][pos * 4]) =
                (u32x2){h[0] | (h[1] << 16), h[2] | (h[3] << 16)};
            *reinterpret_cast<u32x2*>(&AsL[row][pos * 4]) =
                (u32x2){l[0] | (l[1] << 16), l[2] | (l[3] << 16)};
        }
        #pragma unroll
        for (int r = 0; r < 4; ++r) {
            const int f = r * 256 + tid;
            const int col = f & 127, kq = (f >> 7) * 4;
            float v[4] = {gb[r][0], gb[r][1], gb[r][2], gb[r][3]};
            if (mB) {
                const int jg = c0 + col, kg = k0 + kq;
                #pragma unroll
                for (int e = 0; e < 4; ++e) v[e] = (jg <= kg + e) ? v[e] : 0.f;
            }
            unsigned h[4], l[4];
            #pragma unroll
            for (int e = 0; e < 4; ++e) split2(v[e], h[e], l[e]);
            *reinterpret_cast<u32x2*>(&BsH[col][kq]) =
                (u32x2){h[0] | (h[1] << 16), h[2] | (h[3] << 16)};
            *reinterpret_cast<u32x2*>(&BsL[col][kq]) =
                (u32x2){l[0] | (l[1] << 16), l[2] | (l[3] << 16)};
        }
        __syncthreads();
        short8 aH[4], aL[4], bH[4], bL[4];
        #pragma unroll
        for (int m = 0; m < 4; ++m) {
            const int row = wm * 64 + m * 16 + l15;
            aH[m] = *reinterpret_cast<const short8*>(&AsH[row][l4 * 8]);
            aL[m] = *reinterpret_cast<const short8*>(&AsL[row][l4 * 8]);
        }
        #pragma unroll
        for (int n = 0; n < 4; ++n) {
            const int col = wn * 64 + n * 16 + l15;
            bH[n] = *reinterpret_cast<const short8*>(&BsH[col][l4 * 8]);
            bL[n] = *reinterpret_cast<const short8*>(&BsL[col][l4 * 8]);
        }
        #pragma unroll
        for (int m = 0; m < 4; ++m)
            #pragma unroll
            for (int n = 0; n < 4; ++n) {
                acc[m][n] = __builtin_amdgcn_mfma_f32_16x16x32_bf16(aH[m], bH[n], acc[m][n], 0, 0, 0);
                acc[m][n] = __builtin_amdgcn_mfma_f32_16x16x32_bf16(aH[m], bL[n], acc[m][n], 0, 0, 0);
                acc[m][n] = __builtin_amdgcn_mfma_f32_16x16x32_bf16(aL[m], bH[n], acc[m][n], 0, 0, 0);
            }
    }
    const bool diag = (bi == bj);
    #pragma unroll
    for (int m = 0; m < 4; ++m) {
        const int i0 = r0 + wm * 64 + m * 16 + l4 * 4;
        #pragma unroll
        for (int n = 0; n < 4; ++n) {
            const int j = c0 + wn * 64 + n * 16 + l15;
            #pragma unroll
            for (int r = 0; r < 4; ++r) {
                float val = acc[m][n][r];
                if (diag && (j > i0 + r)) val = 0.f;
                C[(size_t)(i0 + r) * N_DIM + j] = val;
            }
        }
    }
}

extern "C" void kernel_launch(void* const* d_in, const int* in_sizes, int n_in,
                              void* d_out, int out_size, void* d_ws, size_t ws_size,
                              hipStream_t stream) {
    const float* A = (const float*)d_in[0];
    const float* B = (const float*)d_in[1];
    float* C = (float*)d_out;
    const size_t planeElems = (size_t)N_DIM * N_DIM;
    if (ws_size >= 2 * planeElems * sizeof(unsigned short)) {   // 64 MiB
        unsigned short* Ah = (unsigned short*)d_ws;
        unsigned short* Bt = Ah + planeElems;
        hipMemsetAsync(d_out, 0, planeElems * sizeof(float), stream);
        hipLaunchKernelGGL(split_A1,  dim3(N_LOWER), dim3(256), 0, stream, A, Ah);
        hipLaunchKernelGGL(split_Bt1, dim3(64, 64),  dim3(256), 0, stream, B, Bt);
        hipLaunchKernelGGL(trimm_seg, dim3(N_LOWER, 2), dim3(256), 0, stream,
                           Ah, Bt, C);
    } else {
        hipLaunchKernelGGL(trimm_fallback, dim3(NT * NT), dim3(256), 0, stream, A, B, C);
    }
}